// Round 1
// baseline (785.939 us; speedup 1.0000x reference)
//
#include <hip/hip_runtime.h>
#include <hip/hip_bf16.h>

#define NODES 4097
#define TT 4096
#define CIN 64
#define HID 128
#define BATCH 64
#define EPS 1e-5f

typedef short bf16x8 __attribute__((ext_vector_type(8)));   // 8 bf16 = 4 VGPRs
typedef float f32x16 __attribute__((ext_vector_type(16)));  // 32x32 acc

// async global->LDS DMA, 16 B per lane; LDS dst = wave-uniform base + lane*16
__device__ __forceinline__ void load_lds16(const void* g, void* l) {
    __builtin_amdgcn_global_load_lds(
        (const __attribute__((address_space(1))) unsigned int*)(uintptr_t)g,
        (__attribute__((address_space(3))) unsigned int*)(uintptr_t)l,
        16, 0, 0);
}

// ---------------- transpose feats (B,C,N) fp32 -> fT (B,N,C) bf16, both encoders ----------------
__global__ __launch_bounds__(256) void k_transpose(const float* __restrict__ f0,
                                                   const float* __restrict__ f1,
                                                   __hip_bfloat16* __restrict__ out) {
    __shared__ float tile[32][33];
    int z = blockIdx.z;
    int enc = z >> 6, b = z & 63;
    const float* in = enc ? f1 : f0;
    __hip_bfloat16* o = out + (size_t)enc * BATCH * NODES * CIN;
    int n0 = blockIdx.x * 32;
    int c0 = blockIdx.y * 32;
    int tx = threadIdx.x, ty = threadIdx.y;  // (32,8)
    for (int i = 0; i < 32; i += 8) {
        int n = n0 + tx, c = c0 + ty + i;
        float v = 0.f;
        if (n < NODES) v = in[((size_t)b * CIN + c) * NODES + n];
        tile[ty + i][tx] = v;
    }
    __syncthreads();
    for (int i = 0; i < 32; i += 8) {
        int n = n0 + ty + i, c = c0 + tx;
        if (n < NODES) o[((size_t)b * NODES + n) * CIN + c] = __float2bfloat16(tile[tx][ty + i]);
    }
}

// ---------------- W (HID,C,3) fp32 -> frag-major bf16 B-operand layout, both encoders ----------------
// Wp id = (ks*4 + ct)*64 + lane holds 8 bf16: B[k=ks*16+(lane>>5)*8+j][n=ct*32+(lane&31)]
// k = slot*C + c; B[k][n] = W[(n*C + c)*3 + slot]
__global__ void k_wprep(const float* __restrict__ W0, const float* __restrict__ W1,
                        __hip_bfloat16* __restrict__ Wp, int C) {
    int enc = blockIdx.y;
    const float* W = enc ? W1 : W0;
    __hip_bfloat16* o = Wp + (size_t)enc * 3 * C * HID;
    int id = blockIdx.x * 256 + threadIdx.x;
    int total = 3 * C * HID / 8;
    if (id >= total) return;
    int lane = id & 63;
    int ct = (id >> 6) & 3;
    int ks = id >> 8;
    int n = ct * 32 + (lane & 31);
    int kb = ks * 16 + (lane >> 5) * 8;
    union { int4 i; __hip_bfloat16 h[8]; } u;
#pragma unroll
    for (int j = 0; j < 8; ++j) {
        int k = kb + j;
        int slot = k / C, c = k % C;
        u.h[j] = __float2bfloat16(W[(n * C + c) * 3 + slot]);
    }
    ((int4*)o)[id] = u.i;
}

// ---------------- gather-conv via MFMA: persistent blocks, B staged ONCE ----------------
// Grid 256 XCD-swizzled (xcd=L&7); block = 8 waves (512 thr), 1 block/CU.
// L&7=xcd, bg=(L>>3)&7 -> b = xcd+8*bg pinned per XCD; enc=(L>>6)&1; half=L>>7.
// Each block: stage the ENTIRE frag-major Wp for its encoder into LDS once
// (conv1 48 KB, conv2 96 KB), one barrier, then loop 8 node-tiles of 256 nodes
// with ZERO barriers: per tile, each lane's A-frags (per-lane 16B gathers) are
// consumed by MFMA and immediately re-gathered for the NEXT tile (single-buffer
// one-tile-deep pipeline -> gather latency hides under ~3k cyc of MFMA).
// sum/sumsq and pool-max accumulate in registers across tiles; one block
// reduction + atomic at the end (LDS scratch overlaid on B after a barrier).
template <int C, bool POOL>
__global__ __launch_bounds__(512, 2) void k_conv_mfma(
    const __hip_bfloat16* __restrict__ xT,    // [2][B][N][C]
    const int* __restrict__ children,
    const __hip_bfloat16* __restrict__ Wp,    // [2][3C*HID] frag-major
    const float* __restrict__ bias0, const float* __restrict__ bias1,
    __hip_bfloat16* __restrict__ y,           // [2][B][N][HID] raw out (if !POOL)
    float* __restrict__ sums,                 // [2B][2]
    float* __restrict__ pool_part) {          // [2B][2][HID] (if POOL)
    constexpr int KSc = C / 16;             // ksteps per child-slot (4 or 8)
    constexpr int KS = 3 * KSc;             // 12 or 24 ksteps total
    constexpr int CH = KS * 4;              // 1-KB LDS chunks (48 or 96)
    constexpr int NT = 8;                   // node-tiles (256 nodes) per block

    __shared__ __align__(16) int4 B_lds[CH * 64];  // 48 or 96 KB

    // ---- XCD-aware decomposition ----
    int L = blockIdx.x;
    int xcd = L & 7;
    int idx = L >> 3;               // 0..31
    int bg = idx & 7;
    int enc = (idx >> 3) & 1;
    int half = idx >> 4;            // which 2048-node half
    int b = xcd + 8 * bg;           // b pinned to one XCD -> gather set stays in L2

    const int tid = threadIdx.x;
    const int lane = tid & 63;
    const int w = tid >> 6;         // wave 0..7
    const int hi = lane >> 5;

    const __hip_bfloat16* x = xT + (size_t)enc * BATCH * NODES * C;
    const int4* WpB = (const int4*)(Wp + (size_t)enc * 3 * C * HID);
    const float* bias = enc ? bias1 : bias0;
    const int sb = enc * BATCH + b;
    const size_t rowbase = (size_t)b * NODES;
    const long cb3 = (long)b * (3 * TT);

    // ---- stage ALL of B once (contiguous, coalesced DMA) ----
#pragma unroll
    for (int i = 0; i < CH / 8; ++i) {
        int chunk = w * (CH / 8) + i;
        load_lds16(WpB + (size_t)chunk * 64 + lane, B_lds + chunk * 64);
    }

    // ---- prologue: gather tile 0's A-frags while DMA drains ----
    const int base_node = half * 2048 + w * 32 + (lane & 31);
    int4 areg[KS];
    {
        const int4* ap[3];
#pragma unroll
        for (int s = 0; s < 3; ++s) {
            int child = children[cb3 + (long)base_node * 3 + s];
            ap[s] = (const int4*)(x + (rowbase + child) * C) + hi;
        }
#pragma unroll
        for (int kk = 0; kk < KS; ++kk) areg[kk] = ap[kk / KSc][(kk % KSc) * 2];
    }
    __syncthreads();  // B_lds ready; the ONLY barrier before the final reduction

    float bsum = 0.f, bss = 0.f;
    float lmax0 = -3.4e38f, lmax1 = -3.4e38f, lmax2 = -3.4e38f, lmax3 = -3.4e38f;
    __hip_bfloat16* yp = POOL ? nullptr : (y + (size_t)enc * BATCH * NODES * HID);

    for (int t = 0; t < NT; ++t) {
        // next tile's gather pointers (issued early; loads land one tile ahead)
        const int4* np[3];
        if (t + 1 < NT) {
            int tnode = base_node + (t + 1) * 256;
#pragma unroll
            for (int s = 0; s < 3; ++s) {
                int child = children[cb3 + (long)tnode * 3 + s];
                np[s] = (const int4*)(x + (rowbase + child) * C) + hi;
            }
        }
        f32x16 acc[4] = {};
#pragma unroll
        for (int kk = 0; kk < KS; ++kk) {
            union { int4 i; bf16x8 v; } a;
            a.i = areg[kk];
#pragma unroll
            for (int cti = 0; cti < 4; ++cti) {
                union { int4 i; bf16x8 v; } bb;
                bb.i = B_lds[(kk * 4 + cti) * 64 + lane];
                acc[cti] = __builtin_amdgcn_mfma_f32_32x32x16_bf16(a.v, bb.v, acc[cti], 0, 0, 0);
            }
            if (t + 1 < NT) areg[kk] = np[kk / KSc][(kk % KSc) * 2];  // refill for next tile
        }
        // ---- epilogue: bias, sums, pool-max / y-write ----
        const int rbase = half * 2048 + t * 256 + w * 32 + 4 * hi + 1;  // +1: node-0 shift
#pragma unroll
        for (int cti = 0; cti < 4; ++cti) {
            int o = cti * 32 + (lane & 31);
            float bv = bias[o];
            f32x16 a2 = acc[cti];
            float lm = -3.4e38f;
#pragma unroll
            for (int reg = 0; reg < 16; ++reg) {
                float v = a2[reg] + bv;
                bsum += v;
                bss += v * v;
                if (POOL) {
                    lm = fmaxf(lm, v);
                } else {
                    int row = rbase + (reg & 3) + 8 * (reg >> 2);
                    yp[(rowbase + row) * HID + o] = __float2bfloat16(v);
                }
            }
            if (POOL) {
                if (cti == 0) lmax0 = fmaxf(lmax0, lm);
                else if (cti == 1) lmax1 = fmaxf(lmax1, lm);
                else if (cti == 2) lmax2 = fmaxf(lmax2, lm);
                else lmax3 = fmaxf(lmax3, lm);
            }
        }
    }

    if (!POOL && half == 0 && tid < HID)
        yp[rowbase * HID + tid] = __float2bfloat16(0.f);  // null-node column

    __syncthreads();  // everyone done reading B_lds; overlay reduction scratch
    float* red = (float*)B_lds;          // [0..1023] sum/sumsq
    float* pm = red + 1024;              // 16 slices x 128 o, o-major
    red[tid] = bsum;
    red[512 + tid] = bss;
    if (POOL) {
        int ob = (w * 2 + hi) * 128 + (lane & 31);
        pm[ob] = lmax0;
        pm[ob + 32] = lmax1;
        pm[ob + 64] = lmax2;
        pm[ob + 96] = lmax3;
    }
    __syncthreads();
    for (int s2 = 256; s2 > 0; s2 >>= 1) {
        if (tid < s2) { red[tid] += red[tid + s2]; red[512 + tid] += red[512 + tid + s2]; }
        __syncthreads();
    }
    if (tid == 0) {
        atomicAdd(&sums[sb * 2], red[0]);
        atomicAdd(&sums[sb * 2 + 1], red[512]);
    }
    if (POOL && tid < HID) {
        float m = -3.4e38f;
#pragma unroll
        for (int s2 = 0; s2 < 16; ++s2) m = fmaxf(m, pm[s2 * 128 + tid]);
        pool_part[((size_t)sb * 2 + half) * HID + tid] = m;
    }
}

// ---------------- per-(enc,b) stats: sum,sumsq -> mean, 1/(std+eps) ----------------
__global__ void k_stats(const float* __restrict__ sums, float* __restrict__ ms) {
    int s = threadIdx.x;  // 128 = 2 enc x 64 b
    const float M = (float)HID * (float)NODES;
    float S = sums[s * 2], SS = sums[s * 2 + 1];
    float mean = S / M;
    float var = (SS - S * S / M) / (M - 1.f);
    float sd = sqrtf(fmaxf(var, 0.f));
    ms[s * 2] = mean;
    ms[s * 2 + 1] = 1.f / (sd + EPS);
}

// ---------------- in-place norm+relu of y1 (bf16 x8 vectorized) ----------------
__global__ __launch_bounds__(256) void k_norm(__hip_bfloat16* __restrict__ y,
                                              const float* __restrict__ ms) {
    constexpr int Q = NODES * HID / 8;  // 65552 int4s per (enc,b) slice
    int s = blockIdx.y;                 // enc*64 + b
    int q = blockIdx.x * 256 + threadIdx.x;
    if (q >= Q) return;
    float mean = ms[s * 2], scale = ms[s * 2 + 1];
    int4* p = (int4*)(y + (size_t)s * NODES * HID) + q;
    union { int4 i; __hip_bfloat16 h[8]; } u;
    u.i = *p;
#pragma unroll
    for (int j = 0; j < 8; ++j) {
        float f = (__bfloat162float(u.h[j]) - mean) * scale;
        u.h[j] = __float2bfloat16(f > 0.f ? f : 0.f);
    }
    *p = u.i;
}

// ---------------- finalize pool: reduce 2 partials, norm+relu ----------------
__global__ __launch_bounds__(128) void k_pool_fin(const float* __restrict__ part,
                                                  const float* __restrict__ ms1,
                                                  float* __restrict__ combined) {
    int b = blockIdx.x, enc = blockIdx.y, o = threadIdx.x;
    int sb = enc * BATCH + b;
    float m = 0.f;  // node-0 raw value is 0
    m = fmaxf(m, part[((size_t)sb * 2 + 0) * HID + o]);
    m = fmaxf(m, part[((size_t)sb * 2 + 1) * HID + o]);
    float v = (m - ms1[sb * 2]) * ms1[sb * 2 + 1];  // monotone: max then transform
    combined[b * 256 + enc * 128 + o] = v > 0.f ? v : 0.f;
}

// ---------------- final FC: mu / logvar ----------------
__global__ __launch_bounds__(128) void k_fc(const float* __restrict__ combined,
                                            const float* __restrict__ Wmu, const float* __restrict__ bmu,
                                            const float* __restrict__ Wlv, const float* __restrict__ blv,
                                            float* __restrict__ out) {
    int b = blockIdx.x;
    int tid = threadIdx.x;
    __shared__ float cb[256];
    cb[tid] = combined[b * 256 + tid];
    cb[tid + 128] = combined[b * 256 + tid + 128];
    __syncthreads();
    const float* W = (tid < 64) ? Wmu : Wlv;
    int l = tid & 63;
    float s = (tid < 64) ? bmu[l] : blv[l];
    for (int j = 0; j < 256; ++j) s += cb[j] * W[l * 256 + j];
    out[(tid < 64 ? 0 : BATCH * 64) + b * 64 + l] = s;
}

extern "C" void kernel_launch(void* const* d_in, const int* in_sizes, int n_in,
                              void* d_out, int out_size, void* d_ws, size_t ws_size,
                              hipStream_t stream) {
    const int* children = (const int*)d_in[2];
    const float* Wmu = (const float*)d_in[11];
    const float* bmu = (const float*)d_in[12];
    const float* Wlv = (const float*)d_in[13];
    const float* blv = (const float*)d_in[14];

    // ---- workspace layout (256B aligned) ----
    char* ws = (char*)d_ws;
    size_t off = 0;
    auto alloc = [&](size_t bytes) { void* p = ws + off; off += (bytes + 255) & ~(size_t)255; return p; };
    float* sums = (float*)alloc(2 * 2 * BATCH * 2 * sizeof(float));  // [layer][enc*B+b][2]
    float* msbuf = (float*)alloc(2 * 2 * BATCH * 2 * sizeof(float));
    float* combined = (float*)alloc((size_t)BATCH * 256 * sizeof(float));
    float* pool_part = (float*)alloc((size_t)2 * BATCH * 2 * HID * sizeof(float));
    __hip_bfloat16* Wp1 = (__hip_bfloat16*)alloc((size_t)2 * 3 * CIN * HID * sizeof(__hip_bfloat16));
    __hip_bfloat16* Wp2 = (__hip_bfloat16*)alloc((size_t)2 * 3 * HID * HID * sizeof(__hip_bfloat16));
    __hip_bfloat16* fT = (__hip_bfloat16*)alloc((size_t)2 * BATCH * NODES * CIN * sizeof(__hip_bfloat16));
    __hip_bfloat16* y1 = (__hip_bfloat16*)alloc((size_t)2 * BATCH * NODES * HID * sizeof(__hip_bfloat16));

    hipMemsetAsync(sums, 0, 2 * 2 * BATCH * 2 * sizeof(float), stream);

    k_wprep<<<dim3(3 * CIN * HID / 8 / 256, 2), 256, 0, stream>>>(
        (const float*)d_in[3], (const float*)d_in[7], Wp1, CIN);
    k_wprep<<<dim3(3 * HID * HID / 8 / 256, 2), 256, 0, stream>>>(
        (const float*)d_in[5], (const float*)d_in[9], Wp2, HID);
    k_transpose<<<dim3(129, 2, 2 * BATCH), dim3(32, 8), 0, stream>>>(
        (const float*)d_in[0], (const float*)d_in[1], fT);

    k_conv_mfma<CIN, false><<<256, 512, 0, stream>>>(
        fT, children, Wp1, (const float*)d_in[4], (const float*)d_in[8], y1, sums, nullptr);
    k_stats<<<1, 128, 0, stream>>>(sums, msbuf);
    k_norm<<<dim3((NODES * HID / 8 + 255) / 256, 2 * BATCH), 256, 0, stream>>>(y1, msbuf);
    k_conv_mfma<HID, true><<<256, 512, 0, stream>>>(
        y1, children, Wp2, (const float*)d_in[6], (const float*)d_in[10], nullptr,
        sums + 256, pool_part);
    k_stats<<<1, 128, 0, stream>>>(sums + 256, msbuf + 256);
    k_pool_fin<<<dim3(BATCH, 2), 128, 0, stream>>>(pool_part, msbuf + 256, combined);

    k_fc<<<BATCH, 128, 0, stream>>>(combined, Wmu, bmu, Wlv, blv, (float*)d_out);
}